// Round 10
// baseline (207.010 us; speedup 1.0000x reference)
//
#include <hip/hip_runtime.h>
#include <math.h>

static const int cN0 = 60000;
static const int cN1 = 15000;
static const int cN2 = 3750;

typedef __bf16 bf16x8 __attribute__((ext_vector_type(8)));
typedef float f32x4 __attribute__((ext_vector_type(4)));

#define GLOAD_LDS16(gsrc, ldst)                                                        \
  __builtin_amdgcn_global_load_lds((const __attribute__((address_space(1))) void*)(gsrc), \
                                   (__attribute__((address_space(3))) void*)(ldst), 16, 0, 0)

// ---------------- prep: pack points(+feat) into float4; transpose weights; zero gmax ----------------
__global__ __launch_bounds__(256) void prep_kernel(
    const float* __restrict__ pts0, const float* __restrict__ feat,
    const float* __restrict__ pts1, const float* __restrict__ pts2,
    const float* __restrict__ W2, const float* __restrict__ W3, const float* __restrict__ W4,
    const float* __restrict__ W5, const float* __restrict__ Wu1, const float* __restrict__ Wu2,
    float4* __restrict__ pk0, float4* __restrict__ pk1, float4* __restrict__ pk2,
    __bf16* __restrict__ T2, __bf16* __restrict__ T3, __bf16* __restrict__ T4,
    __bf16* __restrict__ T5, __bf16* __restrict__ Tu1, __bf16* __restrict__ Tu2,
    unsigned* __restrict__ gm) {
  int role = blockIdx.y;
  int tid = blockIdx.x * 256 + threadIdx.x;
  int stride = gridDim.x * 256;
  if (role == 0 && tid == 0) gm[0] = 0u;
  if (role < 3) {
    const float* p = role == 0 ? pts0 : (role == 1 ? pts1 : pts2);
    float4* o = role == 0 ? pk0 : (role == 1 ? pk1 : pk2);
    int n = role == 0 ? cN0 : (role == 1 ? cN1 : cN2);
    for (int i = tid; i < n; i += stride) {
      float4 v;
      v.x = p[(size_t)i * 3 + 0];
      v.y = p[(size_t)i * 3 + 1];
      v.z = p[(size_t)i * 3 + 2];
      v.w = role == 0 ? feat[i] : 0.f;
      o[i] = v;
    }
  } else {
    const float* src;
    __bf16* dst;
    int Kd, Nd;
    switch (role) {
      case 3: src = W2;  dst = T2;  Kd = 960;  Nd = 64;  break;
      case 4: src = W3;  dst = T3;  Kd = 960;  Nd = 128; break;
      case 5: src = W4;  dst = T4;  Kd = 1920; Nd = 128; break;
      case 6: src = W5;  dst = T5;  Kd = 1920; Nd = 256; break;
      case 7: src = Wu1; dst = Tu1; Kd = 384;  Nd = 128; break;
      default: src = Wu2; dst = Tu2; Kd = 192; Nd = 32;  break;
    }
    int total = Kd * Nd;
    for (int e = tid; e < total; e += stride) {
      int n = e / Kd, k = e % Kd;
      dst[e] = (__bf16)src[(size_t)k * Nd + n];
    }
  }
}

// ---------------- L1 kpconv: Cin=1 -> 64, 32 points/block (512 thr), packed float4 gather -------
__global__ __launch_bounds__(512) void kpconv_l1(
    const float4* __restrict__ pk, const int* __restrict__ neigh,
    const float* __restrict__ kpts, const float* __restrict__ W1,
    __bf16* __restrict__ f0, float extent) {
  const int t = threadIdx.x;
  const int n0b = blockIdx.x * 32;
  __shared__ float s_nb[32][32][4];   // [k][pt][xyzf]
  __shared__ float s_fk[32][16];      // [pt][p]
  __shared__ float s_W[960];
  for (int i = t; i < 960; i += 512) s_W[i] = W1[i];
  #pragma unroll
  for (int i = 0; i < 2; ++i) {
    int e = t + i * 512;
    int pt = e & 31, k = e >> 5;
    int idx = neigh[(size_t)(n0b + pt) * 32 + k];
    *(float4*)&s_nb[k][pt][0] = pk[idx];
  }
  __syncthreads();
  const int lane = t & 63, wave = t >> 6;
  const int g = lane >> 4, p_raw = lane & 15;
  const int p = p_raw < 15 ? p_raw : 0;
  const int pt = wave * 4 + g;
  const int n = n0b + pt;
  const float inv = 1.f / extent;
  float4 q = pk[n];
  const float kx = q.x + kpts[p * 3 + 0] * extent;
  const float ky = q.y + kpts[p * 3 + 1] * extent;
  const float kz = q.z + kpts[p * 3 + 2] * extent;
  float fk = 0.f;
  #pragma unroll 8
  for (int k = 0; k < 32; ++k) {
    f32x4 rec = *(const f32x4*)&s_nb[k][pt][0];
    float dx = rec[0] - kx, dy = rec[1] - ky, dz = rec[2] - kz;
    float d = sqrtf(dx * dx + dy * dy + dz * dz);
    fk += fmaxf(0.f, 1.f - d * inv) * rec[3];
  }
  if (p_raw < 15) s_fk[pt][p_raw] = fk;
  __syncthreads();
  #pragma unroll
  for (int o = 0; o < 4; ++o) {
    int e = o * 512 + t;
    int opt = e >> 6, c = e & 63;
    float acc = 0.f;
    #pragma unroll
    for (int pp = 0; pp < 15; ++pp) acc += s_fk[opt][pp] * s_W[pp * 64 + c];
    acc = acc > 0.f ? acc : 0.1f * acc;
    f0[(size_t)(n0b + opt) * 64 + c] = (__bf16)acc;
  }
}

// ---------------- FUSED kpconv layer: agg (LDS fk) + GEMM ----------------
// SB=true: single-barrier phase-1 with TRIPLE-buffered F and infl (stage target's last
// reader is 2 iterations old => >=1 barrier separates write from read). Used for L4/L5
// (1 block/CU, LDS headroom). L2/L3 keep SB=false (extra bufs would drop 2->1 blocks/CU).
template <int CIN, int COUT, int BM, bool BDBUF, bool SB>
__global__ __launch_bounds__(512) void kpconv_fused(
    const float4* __restrict__ qp, const float4* __restrict__ sp,
    const int* __restrict__ neigh, const __bf16* __restrict__ F,
    const float* __restrict__ kpts, const __bf16* __restrict__ BT,
    __bf16* __restrict__ out, int M, float extent) {
  constexpr int KK = 15 * CIN;
  constexpr int KT = KK / 64;
  constexpr int CPRow = CIN / 8;
  constexpr int G = CIN / 64;
  constexpr int GS = 64 / G;
  constexpr int NB = BM / 2;
  constexpr int CPW = CIN / 64;
  constexpr int FBUF = 64 * CIN;
  constexpr int NFB = SB ? 3 : 2;          // F staging buffers
  constexpr int NIB = SB ? 3 : 1;          // infl buffers
  constexpr int RG = BM / 16;
  constexpr int CG = 8 / RG;
  constexpr int NJ = COUT / (16 * CG);
  constexpr int SMEM_FK = BM * KK * 2;
  constexpr int SMEM = SMEM_FK + NIB * 2560 + BM * 16 + NFB * FBUF * 2;

  __shared__ __align__(16) char smem[SMEM];
  __bf16* s_fk   = (__bf16*)smem;
  __bf16* s_infl = (__bf16*)(smem + SMEM_FK);                          // [NIB][2][640]
  float4* s_q    = (float4*)(smem + SMEM_FK + NIB * 2560);
  __bf16* s_F    = (__bf16*)(smem + SMEM_FK + NIB * 2560 + BM * 16);   // [NFB][FBUF]
  __bf16* s_B    = s_F;

  const int t = threadIdx.x;
  const int w = t >> 6, l = t & 63;
  const int c16 = l & 15, g4 = l >> 4;
  const int m0 = blockIdx.x * BM;
  const int* nb_base = neigh + (size_t)m0 * 32;
  int rlim = (M - m0) * 32 - 1;
  if (rlim > BM * 32 - 1) rlim = BM * 32 - 1;

  const int gb = t / CPRow;
  const int ch = t % CPRow;
  int idxg[NB][G];
  #pragma unroll
  for (int b = 0; b < NB; ++b)
    #pragma unroll
    for (int j = 0; j < G; ++j) {
      int r = b * 64 + gb + j * GS;
      idxg[b][j] = nb_base[r < rlim ? r : rlim];
    }
  const int row_i = (t >> 2) & 63;
  const int pq4 = (t & 3) * 4;
  const int pt_i = row_i >> 5, kk_i = row_i & 31;
  int idxi[NB];
  #pragma unroll
  for (int b = 0; b < NB; ++b) {
    int r = b * 64 + row_i;
    idxi[b] = nb_base[r < rlim ? r : rlim];
  }
  const float inv = 1.f / extent;
  float kpx[4], kpy[4], kpz[4];
  #pragma unroll
  for (int pi = 0; pi < 4; ++pi) {
    int p = pq4 + pi; if (p > 14) p = 14;
    kpx[pi] = kpts[p * 3 + 0] * extent;
    kpy[pi] = kpts[p * 3 + 1] * extent;
    kpz[pi] = kpts[p * 3 + 2] * extent;
  }
  if (t < BM) { int n = m0 + t; s_q[t] = qp[n < M ? n : M - 1]; }

  auto stageF = [&](int buf, const int (&ig)[G]) {
    #pragma unroll
    for (int j = 0; j < G; ++j) {
      int k = (gb + j * GS) & 31;
      const __bf16* src = F + (size_t)ig[j] * CIN + (ch ^ ((k >> 3) & 3)) * 8;
      GLOAD_LDS16(src, s_F + buf * FBUF + (j * 512 + t) * 8);
    }
  };
  auto inflC = [&](const float4& spv, int b, float (&v)[4]) {
    float4 q = s_q[b * 2 + pt_i];
    float sx = spv.x - q.x, sy = spv.y - q.y, sz = spv.z - q.z;
    #pragma unroll
    for (int pi = 0; pi < 4; ++pi) {
      float dx = sx - kpx[pi], dy = sy - kpy[pi], dz = sz - kpz[pi];
      float d = sqrtf(dx * dx + dy * dy + dz * dz);
      v[pi] = fmaxf(0.f, 1.f - d * inv);
    }
  };
  auto inflStore = [&](const float (&v)[4], int ibuf) {
    if (t < 256) {
      #pragma unroll
      for (int pi = 0; pi < 4; ++pi) {
        int p = pq4 + pi;
        if (p < 15) s_infl[ibuf * 1280 + pt_i * 640 + p * 40 + kk_i] = (__bf16)v[pi];
      }
    }
  };
  auto mfmaBatch = [&](int b, int fbuf, int ibuf) {
    const int pt_loc = w / 4;
    const int cc0 = (w & 3) * CPW;
    const __bf16* Fb = s_F + fbuf * FBUF + pt_loc * (32 * CIN);
    bf16x8 a = *(const bf16x8*)&s_infl[ibuf * 1280 + pt_loc * 640 + c16 * 40 + g4 * 8];
    const int row = b * 2 + pt_loc;
    #pragma unroll
    for (int ci = 0; ci < CPW; ++ci) {
      const int cc = cc0 + ci;
      const int Lc = cc * 2 + (c16 >> 3);
      const int pc = Lc ^ g4;
      bf16x8 bv;
      #pragma unroll
      for (int j = 0; j < 8; ++j)
        bv[j] = Fb[(g4 * 8 + j) * CIN + pc * 8 + (c16 & 7)];
      f32x4 acc = __builtin_amdgcn_mfma_f32_16x16x32_bf16(a, bv, (f32x4){0.f, 0.f, 0.f, 0.f}, 0, 0, 0);
      #pragma unroll
      for (int r = 0; r < 4; ++r) {
        int p = g4 * 4 + r;
        if (p < 15) {
          int Lf = p * CPRow + Lc;
          int phys = (Lf & ~7) | ((Lf & 7) ^ (row & 7));
          s_fk[(size_t)row * KK + phys * 8 + (c16 & 7)] = (__bf16)acc[r];
        }
      }
    }
  };

  // publish s_q
  asm volatile("s_waitcnt lgkmcnt(0)" ::: "memory");
  __builtin_amdgcn_s_barrier();
  __builtin_amdgcn_sched_barrier(0);

  float4 spc, spn;
  if (SB) {
    // ---- single-barrier pipelined agg (3-buf F, 3-buf infl) ----
    stageF(0, idxg[0]);
    float4 sp0 = sp[idxi[0]];
    spc = sp[idxi[1 < NB ? 1 : 0]];
    float v0[4];
    inflC(sp0, 0, v0);
    inflStore(v0, 0);
    __builtin_amdgcn_sched_barrier(0);
    asm volatile("s_waitcnt lgkmcnt(0)" ::: "memory");
    __builtin_amdgcn_s_barrier();
    __builtin_amdgcn_sched_barrier(0);
    #pragma unroll
    for (int b = 0; b < NB; ++b) {
      if (b + 1 < NB) stageF((b + 1) % 3, idxg[b + 1]);
      if (b + 2 < NB) spn = sp[idxi[b + 2]];
      if (b + 1 < NB) {
        float vn[4];
        inflC(spc, b + 1, vn);
        inflStore(vn, (b + 1) % 3);
        if (b + 2 < NB) spc = spn;
      }
      __builtin_amdgcn_sched_barrier(0);
      if (b + 1 < NB) {
        if (b + 2 < NB) { if (G == 1) asm volatile("s_waitcnt vmcnt(2)" ::: "memory");
                          else        asm volatile("s_waitcnt vmcnt(3)" ::: "memory"); }
        else            { if (G == 1) asm volatile("s_waitcnt vmcnt(1)" ::: "memory");
                          else        asm volatile("s_waitcnt vmcnt(2)" ::: "memory"); }
      } else {
        asm volatile("s_waitcnt vmcnt(0)" ::: "memory");
      }
      asm volatile("s_waitcnt lgkmcnt(0)" ::: "memory");
      __builtin_amdgcn_s_barrier();
      __builtin_amdgcn_sched_barrier(0);
      mfmaBatch(b, b % 3, b % 3);
    }
    __syncthreads();
  } else {
    // ---- 2-barrier pipelined agg (2-buf F, 1-buf infl) ----
    {
      stageF(0, idxg[0]);
      float4 sp0 = sp[idxi[0]];
      spc = sp[idxi[1 < NB ? 1 : 0]];
      float v0[4];
      inflC(sp0, 0, v0);
      inflStore(v0, 0);
    }
    __builtin_amdgcn_sched_barrier(0);
    #pragma unroll
    for (int b = 0; b < NB; ++b) {
      if (b + 1 < NB) stageF((b + 1) & 1, idxg[b + 1]);
      if (b + 2 < NB) spn = sp[idxi[b + 2]];
      float vn[4];
      if (b + 1 < NB) inflC(spc, b + 1, vn);
      if (b == NB - 1)      { asm volatile("s_waitcnt vmcnt(0)" ::: "memory"); }
      else if (b == NB - 2) { if (G == 1) asm volatile("s_waitcnt vmcnt(1)" ::: "memory");
                              else        asm volatile("s_waitcnt vmcnt(2)" ::: "memory"); }
      else                  { if (G == 1) asm volatile("s_waitcnt vmcnt(2)" ::: "memory");
                              else        asm volatile("s_waitcnt vmcnt(3)" ::: "memory"); }
      asm volatile("s_waitcnt lgkmcnt(0)" ::: "memory");
      __builtin_amdgcn_s_barrier();
      __builtin_amdgcn_sched_barrier(0);
      mfmaBatch(b, b & 1, 0);
      asm volatile("s_waitcnt lgkmcnt(0)" ::: "memory");
      __builtin_amdgcn_s_barrier();
      __builtin_amdgcn_sched_barrier(0);
      if (b + 1 < NB) { inflStore(vn, 0); spc = spn; }
    }
    __syncthreads();
  }

  // ---- phase 2: GEMM fk[BM][KK] x BT[COUT][KK]^T ----
  const int wr = w / CG, wc = w % CG;
  f32x4 acc[NJ];
  #pragma unroll
  for (int j = 0; j < NJ; ++j) acc[j] = (f32x4){0.f, 0.f, 0.f, 0.f};
  auto stageB = [&](int buf, int kt) {
    #pragma unroll
    for (int rnd = 0; rnd < COUT / 64; ++rnd) {
      int slot = rnd * 512 + t;
      int row = slot >> 3, bch = slot & 7;
      GLOAD_LDS16(BT + (size_t)row * KK + kt * 64 + (bch ^ (row & 7)) * 8,
                  s_B + buf * (COUT * 64) + slot * 8);
    }
  };
  const __bf16* fkrow = s_fk + (size_t)(wr * 16 + c16) * KK;
  auto computeTile = [&](int kt, int buf) {
    bf16x8 af[2];
    #pragma unroll
    for (int s = 0; s < 2; ++s)
      af[s] = *(const bf16x8*)&fkrow[(kt * 8 + ((s * 4 + g4) ^ (c16 & 7))) * 8];
    const __bf16* Bb = s_B + buf * (COUT * 64);
    #pragma unroll
    for (int j = 0; j < NJ; ++j) {
      int n = wc * (16 * NJ) + j * 16 + c16;
      #pragma unroll
      for (int s = 0; s < 2; ++s) {
        bf16x8 bf = *(const bf16x8*)&Bb[n * 64 + ((s * 4 + g4) ^ (n & 7)) * 8];
        acc[j] = __builtin_amdgcn_mfma_f32_16x16x32_bf16(af[s], bf, acc[j], 0, 0, 0);
      }
    }
  };
  if (BDBUF) {
    stageB(0, 0);
    __syncthreads();
    for (int kt = 0; kt < KT; ++kt) {
      if (kt + 1 < KT) stageB((kt + 1) & 1, kt + 1);
      computeTile(kt, kt & 1);
      __syncthreads();
    }
  } else {
    for (int kt = 0; kt < KT; ++kt) {
      stageB(0, kt);
      __syncthreads();
      computeTile(kt, 0);
      __syncthreads();
    }
  }
  #pragma unroll
  for (int j = 0; j < NJ; ++j)
    #pragma unroll
    for (int r = 0; r < 4; ++r) {
      int row = m0 + wr * 16 + g4 * 4 + r;
      int col = wc * (16 * NJ) + j * 16 + c16;
      if (row < M) {
        float v = acc[j][r];
        v = v > 0.f ? v : 0.1f * v;
        out[(size_t)row * COUT + col] = (__bf16)v;
      }
    }
}

// ---------------- MFMA bf16 GEMM (decoder D1) ----------------
template <bool LEAKY, bool GATHER>
__global__ __launch_bounds__(256, 2) void gemm_mfma(
    const __bf16* __restrict__ A1, const __bf16* __restrict__ A2,
    const int* __restrict__ gidx, const int K1,
    const __bf16* __restrict__ BT, __bf16* __restrict__ Cout,
    const int M, const int N, const int KK) {
  __shared__ __bf16 sA[2][4096];
  __shared__ __bf16 sB[2][4096];
  const int t = threadIdx.x;
  const int lane = t & 63, wave = t >> 6;
  const int wr = wave >> 1, wc = wave & 1;
  const int m0 = blockIdx.y * 64, n0 = blockIdx.x * 64;
  const int K2 = KK - K1;

  const __bf16* a1row[2];
  const __bf16* a2row[2];
  const __bf16* brow_[2];
  int csrc[2], wbase[2];
  #pragma unroll
  for (int r = 0; r < 2; ++r) {
    int slot = r * 256 + wave * 64 + lane;
    int row = slot >> 3;
    csrc[r] = ((slot & 7) ^ (row & 7)) * 8;
    wbase[r] = (r * 256 + wave * 64) * 8;
    int gm = m0 + row; if (gm > M - 1) gm = M - 1;
    if (GATHER) {
      a1row[r] = A1 + (size_t)gidx[gm] * K1;
      a2row[r] = A2 + (size_t)gm * (size_t)K2;
    } else {
      a1row[r] = A1 + (size_t)gm * (size_t)KK;
    }
    int gn = n0 + row; if (gn > N - 1) gn = N - 1;
    brow_[r] = BT + (size_t)gn * (size_t)KK;
  }

  int offA[2][2], offB[2][2];
  #pragma unroll
  for (int i = 0; i < 2; ++i)
    #pragma unroll
    for (int s = 0; s < 2; ++s) {
      int ra = wr * 32 + i * 16 + (lane & 15);
      int rb = wc * 32 + i * 16 + (lane & 15);
      int chn = s * 4 + (lane >> 4);
      offA[i][s] = ra * 64 + (chn ^ (ra & 7)) * 8;
      offB[i][s] = rb * 64 + (chn ^ (rb & 7)) * 8;
    }

  f32x4 acc[2][2];
  #pragma unroll
  for (int i = 0; i < 2; ++i)
    #pragma unroll
    for (int j = 0; j < 2; ++j) acc[i][j] = (f32x4){0.f, 0.f, 0.f, 0.f};

  auto stage = [&](int buf, int k0) {
    #pragma unroll
    for (int r = 0; r < 2; ++r) {
      int kg = k0 + csrc[r];
      const __bf16* asrc;
      if (GATHER) asrc = (kg < K1) ? (a1row[r] + kg) : (a2row[r] + (kg - K1));
      else        asrc = a1row[r] + kg;
      GLOAD_LDS16(asrc, &sA[buf][wbase[r]]);
      GLOAD_LDS16(brow_[r] + kg, &sB[buf][wbase[r]]);
    }
  };

  stage(0, 0);
  __syncthreads();
  const int nk = KK >> 6;
  int cur = 0;
  for (int kt = 0; kt < nk; ++kt) {
    if (kt + 1 < nk) stage(cur ^ 1, (kt + 1) << 6);
    #pragma unroll
    for (int s = 0; s < 2; ++s) {
      bf16x8 a0 = *(const bf16x8*)&sA[cur][offA[0][s]];
      bf16x8 a1 = *(const bf16x8*)&sA[cur][offA[1][s]];
      bf16x8 b0 = *(const bf16x8*)&sB[cur][offB[0][s]];
      bf16x8 b1 = *(const bf16x8*)&sB[cur][offB[1][s]];
      acc[0][0] = __builtin_amdgcn_mfma_f32_16x16x32_bf16(a0, b0, acc[0][0], 0, 0, 0);
      acc[0][1] = __builtin_amdgcn_mfma_f32_16x16x32_bf16(a0, b1, acc[0][1], 0, 0, 0);
      acc[1][0] = __builtin_amdgcn_mfma_f32_16x16x32_bf16(a1, b0, acc[1][0], 0, 0, 0);
      acc[1][1] = __builtin_amdgcn_mfma_f32_16x16x32_bf16(a1, b1, acc[1][1], 0, 0, 0);
    }
    __syncthreads();
    cur ^= 1;
  }

  #pragma unroll
  for (int i = 0; i < 2; ++i)
    #pragma unroll
    for (int j = 0; j < 2; ++j)
      #pragma unroll
      for (int g = 0; g < 4; ++g) {
        int row = m0 + wr * 32 + i * 16 + (lane >> 4) * 4 + g;
        int col = n0 + wc * 32 + j * 16 + (lane & 15);
        if (row < M && col < N) {
          float v = acc[i][j][g];
          if (LEAKY) v = v > 0.f ? v : 0.1f * v;
          Cout[(size_t)row * N + col] = (__bf16)v;
        }
      }
}

// ---------------- D2: f6[M,32] (f32) = concat(f5[up0], f0) @ Wu2, fused gmax ----------------
// f6 MUST stay f32: detection's (fown == colmax) equality test is discontinuous;
// bf16 rounding creates spurious ties (Round-8 failure: scores absmax 0.87).
__global__ __launch_bounds__(256) void d2_kernel(
    const __bf16* __restrict__ f5b, const __bf16* __restrict__ f0b,
    const int* __restrict__ up0, const __bf16* __restrict__ BT,
    float* __restrict__ f6, int M, unsigned* __restrict__ gmax) {
  __shared__ __bf16 sA[128 * 192];
  __shared__ __bf16 sB[32 * 192];
  __shared__ int s_g[128];
  __shared__ float s_max[4];
  const int t = threadIdx.x;
  const int m0 = blockIdx.x * 128;
  if (t < 128) { int m = m0 + t; s_g[t] = up0[m < M ? m : M - 1]; }
  __syncthreads();
  #pragma unroll
  for (int rnd = 0; rnd < 3; ++rnd) {
    int slot = rnd * 256 + t;
    int row = slot / 24, chd = slot % 24;
    int chs = (chd & ~7) | ((chd & 7) ^ (row & 7));
    GLOAD_LDS16(BT + (size_t)row * 192 + chs * 8, sB + slot * 8);
  }
  #pragma unroll
  for (int rnd = 0; rnd < 12; ++rnd) {
    int slot = rnd * 256 + t;
    int row = slot / 24, chd = slot % 24;
    int chs = (chd & ~7) | ((chd & 7) ^ (row & 7));
    int m = m0 + row; if (m > M - 1) m = M - 1;
    const __bf16* src = (chs < 16) ? (f5b + (size_t)s_g[row] * 128 + chs * 8)
                                   : (f0b + (size_t)m * 64 + (chs - 16) * 8);
    GLOAD_LDS16(src, sA + slot * 8);
  }
  __syncthreads();
  const int w = t >> 6, lane = t & 63;
  const int c16 = lane & 15, g4 = lane >> 4;
  f32x4 acc[2][2];
  #pragma unroll
  for (int i = 0; i < 2; ++i)
    #pragma unroll
    for (int j = 0; j < 2; ++j) acc[i][j] = (f32x4){0.f, 0.f, 0.f, 0.f};
  #pragma unroll
  for (int ks = 0; ks < 6; ++ks) {
    bf16x8 a[2], b[2];
    #pragma unroll
    for (int i = 0; i < 2; ++i) {
      int row = w * 32 + i * 16 + c16;
      int chunk = ks * 4 + g4;
      int phys = (chunk & ~7) | ((chunk & 7) ^ (row & 7));
      a[i] = *(const bf16x8*)&sA[(row * 24 + phys) * 8];
    }
    #pragma unroll
    for (int j = 0; j < 2; ++j) {
      int n = j * 16 + c16;
      int chunk = ks * 4 + g4;
      int phys = (chunk & ~7) | ((chunk & 7) ^ (n & 7));
      b[j] = *(const bf16x8*)&sB[(n * 24 + phys) * 8];
    }
    #pragma unroll
    for (int i = 0; i < 2; ++i)
      #pragma unroll
      for (int j = 0; j < 2; ++j)
        acc[i][j] = __builtin_amdgcn_mfma_f32_16x16x32_bf16(a[i], b[j], acc[i][j], 0, 0, 0);
  }
  float lmax = 0.f;
  #pragma unroll
  for (int i = 0; i < 2; ++i)
    #pragma unroll
    for (int j = 0; j < 2; ++j)
      #pragma unroll
      for (int g = 0; g < 4; ++g) {
        int row = m0 + w * 32 + i * 16 + g4 * 4 + g;
        int col = j * 16 + c16;
        if (row < M) {
          float v = acc[i][j][g];
          lmax = fmaxf(lmax, v);
          f6[(size_t)row * 32 + col] = v;
        }
      }
  #pragma unroll
  for (int s = 32; s >= 1; s >>= 1) lmax = fmaxf(lmax, __shfl_xor(lmax, s, 64));
  if (lane == 0) s_max[w] = lmax;
  __syncthreads();
  if (t == 0) {
    float mm = fmaxf(fmaxf(s_max[0], s_max[1]), fmaxf(s_max[2], s_max[3]));
    atomicMax(gmax, __float_as_uint(mm));
  }
}

// ---------------- detection + fnorm from f32 f6; 16 points/block (512 thr) ----------------
__global__ __launch_bounds__(512) void detect_kernel(
    const float* __restrict__ f6, const int* __restrict__ neigh,
    const float* __restrict__ gm_ptr, float* __restrict__ out_fnorm,
    float* __restrict__ out_scores, int N) {
  int n = blockIdx.x * 16 + (threadIdx.x >> 5);
  int c = threadIdx.x & 31;
  if (n >= N) return;
  float denom = gm_ptr[0] + 1e-6f;
  float fown = f6[(size_t)n * 32 + c];
  int idx_l = neigh[(size_t)n * 32 + c];
  float colsum = 0.f, colmax = -1e30f;
  #pragma unroll 4
  for (int k = 0; k < 32; ++k) {
    int idx = __shfl(idx_l, k, 32);
    float v = f6[(size_t)idx * 32 + c];
    colsum += v;
    colmax = fmaxf(colmax, v);
  }
  float fs = fown / denom;
  float mean = (colsum / denom) * (1.f / 32.f);
  float x = fs - mean;
  float lms = fmaxf(x, 0.f) + log1pf(expf(-fabsf(x)));  // softplus
  float dm = fs;
  #pragma unroll
  for (int s = 16; s >= 1; s >>= 1) dm = fmaxf(dm, __shfl_xor(dm, s, 32));
  float as = lms * fs / (1e-6f + dm);
  float sc = as;
  #pragma unroll
  for (int s = 16; s >= 1; s >>= 1) sc = fmaxf(sc, __shfl_xor(sc, s, 32));
  float det = (fown == colmax) ? 1.f : 0.f;
  #pragma unroll
  for (int s = 16; s >= 1; s >>= 1) det = fmaxf(det, __shfl_xor(det, s, 32));
  float nn2 = fown * fown;
  #pragma unroll
  for (int s = 16; s >= 1; s >>= 1) nn2 += __shfl_xor(nn2, s, 32);
  float inv_nrm = 1.f / fmaxf(sqrtf(nn2), 1e-12f);
  out_fnorm[(size_t)n * 32 + c] = fown * inv_nrm;
  if (c == 0) out_scores[n] = sc * det;
}

extern "C" void kernel_launch(void* const* d_in, const int* in_sizes, int n_in,
                              void* d_out, int out_size, void* d_ws, size_t ws_size,
                              hipStream_t stream) {
  const float* features  = (const float*)d_in[0];
  const float* points0   = (const float*)d_in[1];
  const float* points1   = (const float*)d_in[2];
  const float* points2   = (const float*)d_in[3];
  const int* neighbors0  = (const int*)d_in[4];
  const int* neighbors1  = (const int*)d_in[5];
  const int* neighbors2  = (const int*)d_in[6];
  const int* pools0      = (const int*)d_in[7];
  const int* pools1      = (const int*)d_in[8];
  const int* upsamples0  = (const int*)d_in[9];
  const int* upsamples1  = (const int*)d_in[10];
  const float* kpoints   = (const float*)d_in[11];
  const float* W1  = (const float*)d_in[12];
  const float* W2  = (const float*)d_in[13];
  const float* W3  = (const float*)d_in[14];
  const float* W4  = (const float*)d_in[15];
  const float* W5  = (const float*)d_in[16];
  const float* Wu1 = (const float*)d_in[17];
  const float* Wu2 = (const float*)d_in[18];

  const float R0 = 0.5f;

  char* wp = (char*)d_ws;
  auto alloc = [&](size_t bytes) {
    char* r = wp;
    wp += (bytes + 255) & ~(size_t)255;
    return r;
  };
  __bf16* f0b  = (__bf16*)alloc((size_t)cN0 * 64 * 2);
  __bf16* f1b  = (__bf16*)alloc((size_t)cN1 * 64 * 2);
  __bf16* f2b  = (__bf16*)alloc((size_t)cN1 * 128 * 2);
  __bf16* f3b  = (__bf16*)alloc((size_t)cN2 * 128 * 2);
  __bf16* f4b  = (__bf16*)alloc((size_t)cN2 * 256 * 2);
  __bf16* f5b  = (__bf16*)alloc((size_t)cN1 * 128 * 2);
  float*  f6   = (float*)alloc((size_t)cN0 * 32 * 4);
  __bf16* WT2  = (__bf16*)alloc(960 * 64 * 2);
  __bf16* WT3  = (__bf16*)alloc(960 * 128 * 2);
  __bf16* WT4  = (__bf16*)alloc(1920 * 128 * 2);
  __bf16* WT5  = (__bf16*)alloc(1920 * 256 * 2);
  __bf16* WTu1 = (__bf16*)alloc(384 * 128 * 2);
  __bf16* WTu2 = (__bf16*)alloc(192 * 32 * 2);
  unsigned* gm = (unsigned*)alloc(256);
  float4* pk0  = (float4*)alloc((size_t)cN0 * 16);
  float4* pk1  = (float4*)alloc((size_t)cN1 * 16);
  float4* pk2  = (float4*)alloc((size_t)cN2 * 16);

  prep_kernel<<<dim3(240, 9), 256, 0, stream>>>(
      points0, features, points1, points2, W2, W3, W4, W5, Wu1, Wu2,
      pk0, pk1, pk2, WT2, WT3, WT4, WT5, WTu1, WTu2, gm);
  kpconv_l1<<<cN0 / 32, 512, 0, stream>>>(pk0, neighbors0, kpoints, W1, f0b, R0);

  // L2: strided, f0 -> f1 [N1,64]   (2 blocks/CU, 2-barrier pipelined)
  kpconv_fused<64, 64, 32, true, false><<<(cN1 + 31) / 32, 512, 0, stream>>>(
      pk1, pk0, pools0, f0b, kpoints, WT2, f1b, cN1, R0);
  // L3: simple, f1 -> f2 [N1,128]
  kpconv_fused<64, 128, 32, false, false><<<(cN1 + 31) / 32, 512, 0, stream>>>(
      pk1, pk1, neighbors1, f1b, kpoints, WT3, f2b, cN1, 2.f * R0);
  // L4: strided, f2 -> f3 [N2,128]  (1 block/CU -> single-barrier 3-buf phase 1)
  kpconv_fused<128, 128, 16, true, true><<<(cN2 + 15) / 16, 512, 0, stream>>>(
      pk2, pk1, pools1, f2b, kpoints, WT4, f3b, cN2, 2.f * R0);
  // L5: simple, f3 -> f4 [N2,256]
  kpconv_fused<128, 256, 16, false, true><<<(cN2 + 15) / 16, 512, 0, stream>>>(
      pk2, pk2, neighbors2, f3b, kpoints, WT5, f4b, cN2, 4.f * R0);

  // D1: f5 = leaky(concat(f4[up1], f2) @ Wu1)
  gemm_mfma<true, true><<<dim3(2, 235), 256, 0, stream>>>(
      f4b, f2b, upsamples1, 256, WTu1, f5b, cN1, 128, 384);
  // D2: f6 (f32) = concat(f5[up0], f0) @ Wu2, fused global max
  d2_kernel<<<(cN0 + 127) / 128, 256, 0, stream>>>(
      f5b, f0b, upsamples0, WTu2, f6, cN0, gm);

  float* out_fnorm = (float*)d_out;
  float* out_scores = out_fnorm + (size_t)cN0 * 32;
  detect_kernel<<<(cN0 + 15) / 16, 512, 0, stream>>>(f6, neighbors0, (const float*)gm,
                                                     out_fnorm, out_scores, cN0);
}

// Round 11
// 203.067 us; speedup vs baseline: 1.0194x; 1.0194x over previous
//
#include <hip/hip_runtime.h>
#include <math.h>

static const int cN0 = 60000;
static const int cN1 = 15000;
static const int cN2 = 3750;

typedef __bf16 bf16x8 __attribute__((ext_vector_type(8)));
typedef float f32x4 __attribute__((ext_vector_type(4)));

#define GLOAD_LDS16(gsrc, ldst)                                                        \
  __builtin_amdgcn_global_load_lds((const __attribute__((address_space(1))) void*)(gsrc), \
                                   (__attribute__((address_space(3))) void*)(ldst), 16, 0, 0)

// ---------------- prep: pack points(+feat) into float4; transpose weights; zero gmax ----------------
__global__ __launch_bounds__(256) void prep_kernel(
    const float* __restrict__ pts0, const float* __restrict__ feat,
    const float* __restrict__ pts1, const float* __restrict__ pts2,
    const float* __restrict__ W2, const float* __restrict__ W3, const float* __restrict__ W4,
    const float* __restrict__ W5, const float* __restrict__ Wu1, const float* __restrict__ Wu2,
    float4* __restrict__ pk0, float4* __restrict__ pk1, float4* __restrict__ pk2,
    __bf16* __restrict__ T2, __bf16* __restrict__ T3, __bf16* __restrict__ T4,
    __bf16* __restrict__ T5, __bf16* __restrict__ Tu1, __bf16* __restrict__ Tu2,
    unsigned* __restrict__ gm) {
  int role = blockIdx.y;
  int tid = blockIdx.x * 256 + threadIdx.x;
  int stride = gridDim.x * 256;
  if (role == 0 && tid == 0) gm[0] = 0u;
  if (role < 3) {
    const float* p = role == 0 ? pts0 : (role == 1 ? pts1 : pts2);
    float4* o = role == 0 ? pk0 : (role == 1 ? pk1 : pk2);
    int n = role == 0 ? cN0 : (role == 1 ? cN1 : cN2);
    for (int i = tid; i < n; i += stride) {
      float4 v;
      v.x = p[(size_t)i * 3 + 0];
      v.y = p[(size_t)i * 3 + 1];
      v.z = p[(size_t)i * 3 + 2];
      v.w = role == 0 ? feat[i] : 0.f;
      o[i] = v;
    }
  } else {
    const float* src;
    __bf16* dst;
    int Kd, Nd;
    switch (role) {
      case 3: src = W2;  dst = T2;  Kd = 960;  Nd = 64;  break;
      case 4: src = W3;  dst = T3;  Kd = 960;  Nd = 128; break;
      case 5: src = W4;  dst = T4;  Kd = 1920; Nd = 128; break;
      case 6: src = W5;  dst = T5;  Kd = 1920; Nd = 256; break;
      case 7: src = Wu1; dst = Tu1; Kd = 384;  Nd = 128; break;
      default: src = Wu2; dst = Tu2; Kd = 192; Nd = 32;  break;
    }
    int total = Kd * Nd;
    for (int e = tid; e < total; e += stride) {
      int n = e / Kd, k = e % Kd;
      dst[e] = (__bf16)src[(size_t)k * Nd + n];
    }
  }
}

// ---------------- L1 kpconv: Cin=1 -> 64, 32 points/block (512 thr), packed float4 gather -------
__global__ __launch_bounds__(512) void kpconv_l1(
    const float4* __restrict__ pk, const int* __restrict__ neigh,
    const float* __restrict__ kpts, const float* __restrict__ W1,
    __bf16* __restrict__ f0, float extent) {
  const int t = threadIdx.x;
  const int n0b = blockIdx.x * 32;
  __shared__ float s_nb[32][32][4];   // [k][pt][xyzf]
  __shared__ float s_fk[32][16];      // [pt][p]
  __shared__ float s_W[960];
  for (int i = t; i < 960; i += 512) s_W[i] = W1[i];
  #pragma unroll
  for (int i = 0; i < 2; ++i) {
    int e = t + i * 512;
    int pt = e & 31, k = e >> 5;
    int idx = neigh[(size_t)(n0b + pt) * 32 + k];
    *(float4*)&s_nb[k][pt][0] = pk[idx];
  }
  __syncthreads();
  const int lane = t & 63, wave = t >> 6;
  const int g = lane >> 4, p_raw = lane & 15;
  const int p = p_raw < 15 ? p_raw : 0;
  const int pt = wave * 4 + g;
  const int n = n0b + pt;
  const float inv = 1.f / extent;
  float4 q = pk[n];
  const float kx = q.x + kpts[p * 3 + 0] * extent;
  const float ky = q.y + kpts[p * 3 + 1] * extent;
  const float kz = q.z + kpts[p * 3 + 2] * extent;
  float fk = 0.f;
  #pragma unroll 8
  for (int k = 0; k < 32; ++k) {
    f32x4 rec = *(const f32x4*)&s_nb[k][pt][0];
    float dx = rec[0] - kx, dy = rec[1] - ky, dz = rec[2] - kz;
    float d = sqrtf(dx * dx + dy * dy + dz * dz);
    fk += fmaxf(0.f, 1.f - d * inv) * rec[3];
  }
  if (p_raw < 15) s_fk[pt][p_raw] = fk;
  __syncthreads();
  #pragma unroll
  for (int o = 0; o < 4; ++o) {
    int e = o * 512 + t;
    int opt = e >> 6, c = e & 63;
    float acc = 0.f;
    #pragma unroll
    for (int pp = 0; pp < 15; ++pp) acc += s_fk[opt][pp] * s_W[pp * 64 + c];
    acc = acc > 0.f ? acc : 0.1f * acc;
    f0[(size_t)(n0b + opt) * 64 + c] = (__bf16)acc;
  }
}

// ---------------- FUSED kpconv layer: agg (LDS fk) + GEMM ----------------
template <int CIN, int COUT, int BM, bool BDBUF>
__global__ __launch_bounds__(512) void kpconv_fused(
    const float4* __restrict__ qp, const float4* __restrict__ sp,
    const int* __restrict__ neigh, const __bf16* __restrict__ F,
    const float* __restrict__ kpts, const __bf16* __restrict__ BT,
    __bf16* __restrict__ out, int M, float extent) {
  constexpr int KK = 15 * CIN;
  constexpr int KT = KK / 64;
  constexpr int CPRow = CIN / 8;
  constexpr int G = CIN / 64;
  constexpr int GS = 64 / G;
  constexpr int NB = BM / 2;
  constexpr int CPW = CIN / 64;
  constexpr int FBUF = 64 * CIN;
  constexpr int RG = BM / 16;
  constexpr int CG = 8 / RG;
  constexpr int NJ = COUT / (16 * CG);
  constexpr int SMEM_FK = BM * KK * 2;
  constexpr int SMEM = SMEM_FK + 2 * 1280 + BM * 16 + 2 * FBUF * 2;

  __shared__ __align__(16) char smem[SMEM];
  __bf16* s_fk   = (__bf16*)smem;
  __bf16* s_infl = (__bf16*)(smem + SMEM_FK);
  float4* s_q    = (float4*)(smem + SMEM_FK + 2 * 1280);
  __bf16* s_F    = (__bf16*)(smem + SMEM_FK + 2 * 1280 + BM * 16);
  __bf16* s_B    = s_F;

  const int t = threadIdx.x;
  const int w = t >> 6, l = t & 63;
  const int c16 = l & 15, g4 = l >> 4;
  const int m0 = blockIdx.x * BM;
  const int* nb_base = neigh + (size_t)m0 * 32;
  int rlim = (M - m0) * 32 - 1;
  if (rlim > BM * 32 - 1) rlim = BM * 32 - 1;

  const int gb = t / CPRow;
  const int ch = t % CPRow;
  int idxg[NB][G];
  #pragma unroll
  for (int b = 0; b < NB; ++b)
    #pragma unroll
    for (int j = 0; j < G; ++j) {
      int r = b * 64 + gb + j * GS;
      idxg[b][j] = nb_base[r < rlim ? r : rlim];
    }
  const int row_i = (t >> 2) & 63;
  const int pq4 = (t & 3) * 4;
  const int pt_i = row_i >> 5, kk_i = row_i & 31;
  int idxi[NB];
  #pragma unroll
  for (int b = 0; b < NB; ++b) {
    int r = b * 64 + row_i;
    idxi[b] = nb_base[r < rlim ? r : rlim];
  }
  const float inv = 1.f / extent;
  float kpx[4], kpy[4], kpz[4];
  #pragma unroll
  for (int pi = 0; pi < 4; ++pi) {
    int p = pq4 + pi; if (p > 14) p = 14;
    kpx[pi] = kpts[p * 3 + 0] * extent;
    kpy[pi] = kpts[p * 3 + 1] * extent;
    kpz[pi] = kpts[p * 3 + 2] * extent;
  }
  if (t < BM) { int n = m0 + t; s_q[t] = qp[n < M ? n : M - 1]; }

  auto stageF = [&](int buf, const int (&ig)[G]) {
    #pragma unroll
    for (int j = 0; j < G; ++j) {
      int k = (gb + j * GS) & 31;
      const __bf16* src = F + (size_t)ig[j] * CIN + (ch ^ ((k >> 3) & 3)) * 8;
      GLOAD_LDS16(src, s_F + buf * FBUF + (j * 512 + t) * 8);
    }
  };
  auto inflC = [&](const float4& spv, int b, float (&v)[4]) {
    float4 q = s_q[b * 2 + pt_i];
    float sx = spv.x - q.x, sy = spv.y - q.y, sz = spv.z - q.z;
    #pragma unroll
    for (int pi = 0; pi < 4; ++pi) {
      float dx = sx - kpx[pi], dy = sy - kpy[pi], dz = sz - kpz[pi];
      float d = sqrtf(dx * dx + dy * dy + dz * dz);
      v[pi] = fmaxf(0.f, 1.f - d * inv);
    }
  };
  auto inflStore = [&](const float (&v)[4]) {
    if (t < 256) {
      #pragma unroll
      for (int pi = 0; pi < 4; ++pi) {
        int p = pq4 + pi;
        if (p < 15) s_infl[pt_i * 640 + p * 40 + kk_i] = (__bf16)v[pi];
      }
    }
  };
  auto mfmaBatch = [&](int b, int buf) {
    const int pt_loc = w / 4;
    const int cc0 = (w & 3) * CPW;
    const __bf16* Fb = s_F + buf * FBUF + pt_loc * (32 * CIN);
    bf16x8 a = *(const bf16x8*)&s_infl[pt_loc * 640 + c16 * 40 + g4 * 8];
    const int row = b * 2 + pt_loc;
    #pragma unroll
    for (int ci = 0; ci < CPW; ++ci) {
      const int cc = cc0 + ci;
      const int Lc = cc * 2 + (c16 >> 3);
      const int pc = Lc ^ g4;
      bf16x8 bv;
      #pragma unroll
      for (int j = 0; j < 8; ++j)
        bv[j] = Fb[(g4 * 8 + j) * CIN + pc * 8 + (c16 & 7)];
      f32x4 acc = __builtin_amdgcn_mfma_f32_16x16x32_bf16(a, bv, (f32x4){0.f, 0.f, 0.f, 0.f}, 0, 0, 0);
      #pragma unroll
      for (int r = 0; r < 4; ++r) {
        int p = g4 * 4 + r;
        if (p < 15) {
          int Lf = p * CPRow + Lc;
          int phys = (Lf & ~7) | ((Lf & 7) ^ (row & 7));
          s_fk[(size_t)row * KK + phys * 8 + (c16 & 7)] = (__bf16)acc[r];
        }
      }
    }
  };

  asm volatile("s_waitcnt lgkmcnt(0)" ::: "memory");
  __builtin_amdgcn_s_barrier();
  __builtin_amdgcn_sched_barrier(0);

  float4 spc, spn;
  {
    stageF(0, idxg[0]);
    float4 sp0 = sp[idxi[0]];
    spc = sp[idxi[1 < NB ? 1 : 0]];
    float v0[4];
    inflC(sp0, 0, v0);
    inflStore(v0);
  }
  __builtin_amdgcn_sched_barrier(0);
  #pragma unroll
  for (int b = 0; b < NB; ++b) {
    if (b + 1 < NB) stageF((b + 1) & 1, idxg[b + 1]);
    if (b + 2 < NB) spn = sp[idxi[b + 2]];
    float vn[4];
    if (b + 1 < NB) inflC(spc, b + 1, vn);
    if (b == NB - 1)      { asm volatile("s_waitcnt vmcnt(0)" ::: "memory"); }
    else if (b == NB - 2) { if (G == 1) asm volatile("s_waitcnt vmcnt(1)" ::: "memory");
                            else        asm volatile("s_waitcnt vmcnt(2)" ::: "memory"); }
    else                  { if (G == 1) asm volatile("s_waitcnt vmcnt(2)" ::: "memory");
                            else        asm volatile("s_waitcnt vmcnt(3)" ::: "memory"); }
    asm volatile("s_waitcnt lgkmcnt(0)" ::: "memory");
    __builtin_amdgcn_s_barrier();
    __builtin_amdgcn_sched_barrier(0);
    mfmaBatch(b, b & 1);
    asm volatile("s_waitcnt lgkmcnt(0)" ::: "memory");
    __builtin_amdgcn_s_barrier();
    __builtin_amdgcn_sched_barrier(0);
    if (b + 1 < NB) { inflStore(vn); spc = spn; }
  }
  __syncthreads();

  const int wr = w / CG, wc = w % CG;
  f32x4 acc[NJ];
  #pragma unroll
  for (int j = 0; j < NJ; ++j) acc[j] = (f32x4){0.f, 0.f, 0.f, 0.f};
  auto stageB = [&](int buf, int kt) {
    #pragma unroll
    for (int rnd = 0; rnd < COUT / 64; ++rnd) {
      int slot = rnd * 512 + t;
      int row = slot >> 3, bch = slot & 7;
      GLOAD_LDS16(BT + (size_t)row * KK + kt * 64 + (bch ^ (row & 7)) * 8,
                  s_B + buf * (COUT * 64) + slot * 8);
    }
  };
  const __bf16* fkrow = s_fk + (size_t)(wr * 16 + c16) * KK;
  auto computeTile = [&](int kt, int buf) {
    bf16x8 af[2];
    #pragma unroll
    for (int s = 0; s < 2; ++s)
      af[s] = *(const bf16x8*)&fkrow[(kt * 8 + ((s * 4 + g4) ^ (c16 & 7))) * 8];
    const __bf16* Bb = s_B + buf * (COUT * 64);
    #pragma unroll
    for (int j = 0; j < NJ; ++j) {
      int n = wc * (16 * NJ) + j * 16 + c16;
      #pragma unroll
      for (int s = 0; s < 2; ++s) {
        bf16x8 bf = *(const bf16x8*)&Bb[n * 64 + ((s * 4 + g4) ^ (n & 7)) * 8];
        acc[j] = __builtin_amdgcn_mfma_f32_16x16x32_bf16(af[s], bf, acc[j], 0, 0, 0);
      }
    }
  };
  if (BDBUF) {
    stageB(0, 0);
    __syncthreads();
    for (int kt = 0; kt < KT; ++kt) {
      if (kt + 1 < KT) stageB((kt + 1) & 1, kt + 1);
      computeTile(kt, kt & 1);
      __syncthreads();
    }
  } else {
    for (int kt = 0; kt < KT; ++kt) {
      stageB(0, kt);
      __syncthreads();
      computeTile(kt, 0);
      __syncthreads();
    }
  }
  #pragma unroll
  for (int j = 0; j < NJ; ++j)
    #pragma unroll
    for (int r = 0; r < 4; ++r) {
      int row = m0 + wr * 16 + g4 * 4 + r;
      int col = wc * (16 * NJ) + j * 16 + c16;
      if (row < M) {
        float v = acc[j][r];
        v = v > 0.f ? v : 0.1f * v;
        out[(size_t)row * COUT + col] = (__bf16)v;
      }
    }
}

// ---------------- MFMA bf16 GEMM (decoder D1) ----------------
template <bool LEAKY, bool GATHER>
__global__ __launch_bounds__(256, 2) void gemm_mfma(
    const __bf16* __restrict__ A1, const __bf16* __restrict__ A2,
    const int* __restrict__ gidx, const int K1,
    const __bf16* __restrict__ BT, __bf16* __restrict__ Cout,
    const int M, const int N, const int KK) {
  __shared__ __bf16 sA[2][4096];
  __shared__ __bf16 sB[2][4096];
  const int t = threadIdx.x;
  const int lane = t & 63, wave = t >> 6;
  const int wr = wave >> 1, wc = wave & 1;
  const int m0 = blockIdx.y * 64, n0 = blockIdx.x * 64;
  const int K2 = KK - K1;

  const __bf16* a1row[2];
  const __bf16* a2row[2];
  const __bf16* brow_[2];
  int csrc[2], wbase[2];
  #pragma unroll
  for (int r = 0; r < 2; ++r) {
    int slot = r * 256 + wave * 64 + lane;
    int row = slot >> 3;
    csrc[r] = ((slot & 7) ^ (row & 7)) * 8;
    wbase[r] = (r * 256 + wave * 64) * 8;
    int gm = m0 + row; if (gm > M - 1) gm = M - 1;
    if (GATHER) {
      a1row[r] = A1 + (size_t)gidx[gm] * K1;
      a2row[r] = A2 + (size_t)gm * (size_t)K2;
    } else {
      a1row[r] = A1 + (size_t)gm * (size_t)KK;
    }
    int gn = n0 + row; if (gn > N - 1) gn = N - 1;
    brow_[r] = BT + (size_t)gn * (size_t)KK;
  }

  int offA[2][2], offB[2][2];
  #pragma unroll
  for (int i = 0; i < 2; ++i)
    #pragma unroll
    for (int s = 0; s < 2; ++s) {
      int ra = wr * 32 + i * 16 + (lane & 15);
      int rb = wc * 32 + i * 16 + (lane & 15);
      int chn = s * 4 + (lane >> 4);
      offA[i][s] = ra * 64 + (chn ^ (ra & 7)) * 8;
      offB[i][s] = rb * 64 + (chn ^ (rb & 7)) * 8;
    }

  f32x4 acc[2][2];
  #pragma unroll
  for (int i = 0; i < 2; ++i)
    #pragma unroll
    for (int j = 0; j < 2; ++j) acc[i][j] = (f32x4){0.f, 0.f, 0.f, 0.f};

  auto stage = [&](int buf, int k0) {
    #pragma unroll
    for (int r = 0; r < 2; ++r) {
      int kg = k0 + csrc[r];
      const __bf16* asrc;
      if (GATHER) asrc = (kg < K1) ? (a1row[r] + kg) : (a2row[r] + (kg - K1));
      else        asrc = a1row[r] + kg;
      GLOAD_LDS16(asrc, &sA[buf][wbase[r]]);
      GLOAD_LDS16(brow_[r] + kg, &sB[buf][wbase[r]]);
    }
  };

  stage(0, 0);
  __syncthreads();
  const int nk = KK >> 6;
  int cur = 0;
  for (int kt = 0; kt < nk; ++kt) {
    if (kt + 1 < nk) stage(cur ^ 1, (kt + 1) << 6);
    #pragma unroll
    for (int s = 0; s < 2; ++s) {
      bf16x8 a0 = *(const bf16x8*)&sA[cur][offA[0][s]];
      bf16x8 a1 = *(const bf16x8*)&sA[cur][offA[1][s]];
      bf16x8 b0 = *(const bf16x8*)&sB[cur][offB[0][s]];
      bf16x8 b1 = *(const bf16x8*)&sB[cur][offB[1][s]];
      acc[0][0] = __builtin_amdgcn_mfma_f32_16x16x32_bf16(a0, b0, acc[0][0], 0, 0, 0);
      acc[0][1] = __builtin_amdgcn_mfma_f32_16x16x32_bf16(a0, b1, acc[0][1], 0, 0, 0);
      acc[1][0] = __builtin_amdgcn_mfma_f32_16x16x32_bf16(a1, b0, acc[1][0], 0, 0, 0);
      acc[1][1] = __builtin_amdgcn_mfma_f32_16x16x32_bf16(a1, b1, acc[1][1], 0, 0, 0);
    }
    __syncthreads();
    cur ^= 1;
  }

  #pragma unroll
  for (int i = 0; i < 2; ++i)
    #pragma unroll
    for (int j = 0; j < 2; ++j)
      #pragma unroll
      for (int g = 0; g < 4; ++g) {
        int row = m0 + wr * 32 + i * 16 + (lane >> 4) * 4 + g;
        int col = n0 + wc * 32 + j * 16 + (lane & 15);
        if (row < M && col < N) {
          float v = acc[i][j][g];
          if (LEAKY) v = v > 0.f ? v : 0.1f * v;
          Cout[(size_t)row * N + col] = (__bf16)v;
        }
      }
}

// ---------------- D2: f6[M,32] (f32) = concat(f5[up0], f0) @ Wu2, fused gmax ----------------
// f6 MUST stay f32: detection's (fown == colmax) equality test is discontinuous;
// bf16 rounding creates spurious ties (Round-8 failure: scores absmax 0.87).
__global__ __launch_bounds__(256) void d2_kernel(
    const __bf16* __restrict__ f5b, const __bf16* __restrict__ f0b,
    const int* __restrict__ up0, const __bf16* __restrict__ BT,
    float* __restrict__ f6, int M, unsigned* __restrict__ gmax) {
  __shared__ __bf16 sA[128 * 192];
  __shared__ __bf16 sB[32 * 192];
  __shared__ int s_g[128];
  __shared__ float s_max[4];
  const int t = threadIdx.x;
  const int m0 = blockIdx.x * 128;
  if (t < 128) { int m = m0 + t; s_g[t] = up0[m < M ? m : M - 1]; }
  __syncthreads();
  #pragma unroll
  for (int rnd = 0; rnd < 3; ++rnd) {
    int slot = rnd * 256 + t;
    int row = slot / 24, chd = slot % 24;
    int chs = (chd & ~7) | ((chd & 7) ^ (row & 7));
    GLOAD_LDS16(BT + (size_t)row * 192 + chs * 8, sB + slot * 8);
  }
  #pragma unroll
  for (int rnd = 0; rnd < 12; ++rnd) {
    int slot = rnd * 256 + t;
    int row = slot / 24, chd = slot % 24;
    int chs = (chd & ~7) | ((chd & 7) ^ (row & 7));
    int m = m0 + row; if (m > M - 1) m = M - 1;
    const __bf16* src = (chs < 16) ? (f5b + (size_t)s_g[row] * 128 + chs * 8)
                                   : (f0b + (size_t)m * 64 + (chs - 16) * 8);
    GLOAD_LDS16(src, sA + slot * 8);
  }
  __syncthreads();
  const int w = t >> 6, lane = t & 63;
  const int c16 = lane & 15, g4 = lane >> 4;
  f32x4 acc[2][2];
  #pragma unroll
  for (int i = 0; i < 2; ++i)
    #pragma unroll
    for (int j = 0; j < 2; ++j) acc[i][j] = (f32x4){0.f, 0.f, 0.f, 0.f};
  #pragma unroll
  for (int ks = 0; ks < 6; ++ks) {
    bf16x8 a[2], b[2];
    #pragma unroll
    for (int i = 0; i < 2; ++i) {
      int row = w * 32 + i * 16 + c16;
      int chunk = ks * 4 + g4;
      int phys = (chunk & ~7) | ((chunk & 7) ^ (row & 7));
      a[i] = *(const bf16x8*)&sA[(row * 24 + phys) * 8];
    }
    #pragma unroll
    for (int j = 0; j < 2; ++j) {
      int n = j * 16 + c16;
      int chunk = ks * 4 + g4;
      int phys = (chunk & ~7) | ((chunk & 7) ^ (n & 7));
      b[j] = *(const bf16x8*)&sB[(n * 24 + phys) * 8];
    }
    #pragma unroll
    for (int i = 0; i < 2; ++i)
      #pragma unroll
      for (int j = 0; j < 2; ++j)
        acc[i][j] = __builtin_amdgcn_mfma_f32_16x16x32_bf16(a[i], b[j], acc[i][j], 0, 0, 0);
  }
  float lmax = 0.f;
  #pragma unroll
  for (int i = 0; i < 2; ++i)
    #pragma unroll
    for (int j = 0; j < 2; ++j)
      #pragma unroll
      for (int g = 0; g < 4; ++g) {
        int row = m0 + w * 32 + i * 16 + g4 * 4 + g;
        int col = j * 16 + c16;
        if (row < M) {
          float v = acc[i][j][g];
          lmax = fmaxf(lmax, v);
          f6[(size_t)row * 32 + col] = v;
        }
      }
  #pragma unroll
  for (int s = 32; s >= 1; s >>= 1) lmax = fmaxf(lmax, __shfl_xor(lmax, s, 64));
  if (lane == 0) s_max[w] = lmax;
  __syncthreads();
  if (t == 0) {
    float mm = fmaxf(fmaxf(s_max[0], s_max[1]), fmaxf(s_max[2], s_max[3]));
    atomicMax(gmax, __float_as_uint(mm));
  }
}

// ---------------- detection + fnorm from f32 f6; 16 points/block (512 thr) ----------------
__global__ __launch_bounds__(512) void detect_kernel(
    const float* __restrict__ f6, const int* __restrict__ neigh,
    const float* __restrict__ gm_ptr, float* __restrict__ out_fnorm,
    float* __restrict__ out_scores, int N) {
  int n = blockIdx.x * 16 + (threadIdx.x >> 5);
  int c = threadIdx.x & 31;
  if (n >= N) return;
  float denom = gm_ptr[0] + 1e-6f;
  float fown = f6[(size_t)n * 32 + c];
  int idx_l = neigh[(size_t)n * 32 + c];
  float colsum = 0.f, colmax = -1e30f;
  for (int k = 0; k < 32; ++k) {
    int idx = __shfl(idx_l, k, 32);
    float v = f6[(size_t)idx * 32 + c];
    colsum += v;
    colmax = fmaxf(colmax, v);
  }
  float fs = fown / denom;
  float mean = (colsum / denom) * (1.f / 32.f);
  float x = fs - mean;
  float lms = fmaxf(x, 0.f) + log1pf(expf(-fabsf(x)));  // softplus
  float dm = fs;
  #pragma unroll
  for (int s = 16; s >= 1; s >>= 1) dm = fmaxf(dm, __shfl_xor(dm, s, 32));
  float as = lms * fs / (1e-6f + dm);
  float sc = as;
  #pragma unroll
  for (int s = 16; s >= 1; s >>= 1) sc = fmaxf(sc, __shfl_xor(sc, s, 32));
  float det = (fown == colmax) ? 1.f : 0.f;
  #pragma unroll
  for (int s = 16; s >= 1; s >>= 1) det = fmaxf(det, __shfl_xor(det, s, 32));
  float nn2 = fown * fown;
  #pragma unroll
  for (int s = 16; s >= 1; s >>= 1) nn2 += __shfl_xor(nn2, s, 32);
  float inv_nrm = 1.f / fmaxf(sqrtf(nn2), 1e-12f);
  out_fnorm[(size_t)n * 32 + c] = fown * inv_nrm;
  if (c == 0) out_scores[n] = sc * det;
}

extern "C" void kernel_launch(void* const* d_in, const int* in_sizes, int n_in,
                              void* d_out, int out_size, void* d_ws, size_t ws_size,
                              hipStream_t stream) {
  const float* features  = (const float*)d_in[0];
  const float* points0   = (const float*)d_in[1];
  const float* points1   = (const float*)d_in[2];
  const float* points2   = (const float*)d_in[3];
  const int* neighbors0  = (const int*)d_in[4];
  const int* neighbors1  = (const int*)d_in[5];
  const int* neighbors2  = (const int*)d_in[6];
  const int* pools0      = (const int*)d_in[7];
  const int* pools1      = (const int*)d_in[8];
  const int* upsamples0  = (const int*)d_in[9];
  const int* upsamples1  = (const int*)d_in[10];
  const float* kpoints   = (const float*)d_in[11];
  const float* W1  = (const float*)d_in[12];
  const float* W2  = (const float*)d_in[13];
  const float* W3  = (const float*)d_in[14];
  const float* W4  = (const float*)d_in[15];
  const float* W5  = (const float*)d_in[16];
  const float* Wu1 = (const float*)d_in[17];
  const float* Wu2 = (const float*)d_in[18];

  const float R0 = 0.5f;

  char* wp = (char*)d_ws;
  auto alloc = [&](size_t bytes) {
    char* r = wp;
    wp += (bytes + 255) & ~(size_t)255;
    return r;
  };
  __bf16* f0b  = (__bf16*)alloc((size_t)cN0 * 64 * 2);
  __bf16* f1b  = (__bf16*)alloc((size_t)cN1 * 64 * 2);
  __bf16* f2b  = (__bf16*)alloc((size_t)cN1 * 128 * 2);
  __bf16* f3b  = (__bf16*)alloc((size_t)cN2 * 128 * 2);
  __bf16* f4b  = (__bf16*)alloc((size_t)cN2 * 256 * 2);
  __bf16* f5b  = (__bf16*)alloc((size_t)cN1 * 128 * 2);
  float*  f6   = (float*)alloc((size_t)cN0 * 32 * 4);
  __bf16* WT2  = (__bf16*)alloc(960 * 64 * 2);
  __bf16* WT3  = (__bf16*)alloc(960 * 128 * 2);
  __bf16* WT4  = (__bf16*)alloc(1920 * 128 * 2);
  __bf16* WT5  = (__bf16*)alloc(1920 * 256 * 2);
  __bf16* WTu1 = (__bf16*)alloc(384 * 128 * 2);
  __bf16* WTu2 = (__bf16*)alloc(192 * 32 * 2);
  unsigned* gm = (unsigned*)alloc(256);
  float4* pk0  = (float4*)alloc((size_t)cN0 * 16);
  float4* pk1  = (float4*)alloc((size_t)cN1 * 16);
  float4* pk2  = (float4*)alloc((size_t)cN2 * 16);

  prep_kernel<<<dim3(240, 9), 256, 0, stream>>>(
      points0, features, points1, points2, W2, W3, W4, W5, Wu1, Wu2,
      pk0, pk1, pk2, WT2, WT3, WT4, WT5, WTu1, WTu2, gm);
  kpconv_l1<<<cN0 / 32, 512, 0, stream>>>(pk0, neighbors0, kpoints, W1, f0b, R0);

  // L2: strided, f0 -> f1 [N1,64]   (2 blocks/CU, 2-barrier pipelined)
  kpconv_fused<64, 64, 32, true><<<(cN1 + 31) / 32, 512, 0, stream>>>(
      pk1, pk0, pools0, f0b, kpoints, WT2, f1b, cN1, R0);
  // L3: simple, f1 -> f2 [N1,128]
  kpconv_fused<64, 128, 32, false><<<(cN1 + 31) / 32, 512, 0, stream>>>(
      pk1, pk1, neighbors1, f1b, kpoints, WT3, f2b, cN1, 2.f * R0);
  // L4: strided, f2 -> f3 [N2,128]
  kpconv_fused<128, 128, 16, true><<<(cN2 + 15) / 16, 512, 0, stream>>>(
      pk2, pk1, pools1, f2b, kpoints, WT4, f3b, cN2, 2.f * R0);
  // L5: simple, f3 -> f4 [N2,256]
  kpconv_fused<128, 256, 16, false><<<(cN2 + 15) / 16, 512, 0, stream>>>(
      pk2, pk2, neighbors2, f3b, kpoints, WT5, f4b, cN2, 4.f * R0);

  // D1: f5 = leaky(concat(f4[up1], f2) @ Wu1)
  gemm_mfma<true, true><<<dim3(2, 235), 256, 0, stream>>>(
      f4b, f2b, upsamples1, 256, WTu1, f5b, cN1, 128, 384);
  // D2: f6 (f32) = concat(f5[up0], f0) @ Wu2, fused global max
  d2_kernel<<<(cN0 + 127) / 128, 256, 0, stream>>>(
      f5b, f0b, upsamples0, WTu2, f6, cN0, gm);

  float* out_fnorm = (float*)d_out;
  float* out_scores = out_fnorm + (size_t)cN0 * 32;
  detect_kernel<<<(cN0 + 15) / 16, 512, 0, stream>>>(f6, neighbors0, (const float*)gm,
                                                     out_fnorm, out_scores, cN0);
}